// Round 2
// baseline (14470.851 us; speedup 1.0000x reference)
//
#include <hip/hip_runtime.h>

// NoPropCTMomentNet: 10-step Euler integration of a 17->64->64->32->8 swish MLP.
// Round 2: fix rule-#20 scratch spill — FULLY unroll all i-loops so every
// activation array index is compile-time constant -> arrays stay in VGPRs.
// Weights are wave-uniform -> scalar loads (SGPR operand to v_fmac).

constexpr int NSTEP = 10;

__device__ __forceinline__ float swish(float x) {
    float s = __builtin_amdgcn_rcpf(1.0f + __expf(-x));
    return x * s;
}

__global__ __launch_bounds__(256, 2) void noprop_f32_kernel(
    const float* __restrict__ eta,
    const float* __restrict__ W1, const float* __restrict__ b1,
    const float* __restrict__ W2, const float* __restrict__ b2,
    const float* __restrict__ W3, const float* __restrict__ b3,
    const float* __restrict__ W4, const float* __restrict__ b4,
    float* __restrict__ out, int batch)
{
    const int row = blockIdx.x * blockDim.x + threadIdx.x;
    if (row >= batch) return;
    const float dt = 0.1f;

    float et[8], st[8];
    {
        const float4* ep = reinterpret_cast<const float4*>(eta + (size_t)row * 8);
        float4 a = ep[0], b = ep[1];
        et[0] = a.x; et[1] = a.y; et[2] = a.z; et[3] = a.w;
        et[4] = b.x; et[5] = b.y; et[6] = b.z; et[7] = b.w;
    }
#pragma unroll
    for (int i = 0; i < 8; ++i) st[i] = et[i];

#pragma unroll 1
    for (int step = 0; step < NSTEP; ++step) {
        const float t = dt * (float)step;

        // ---- layer 1: x = [st(8), et(8), t] @ W1[17,64] + b1, swish
        float h1[64];
#pragma unroll
        for (int j = 0; j < 64; ++j) h1[j] = fmaf(t, W1[16 * 64 + j], b1[j]);
#pragma unroll
        for (int i = 0; i < 8; ++i) {
#pragma unroll
            for (int j = 0; j < 64; ++j) h1[j] = fmaf(st[i], W1[i * 64 + j], h1[j]);
        }
#pragma unroll
        for (int i = 0; i < 8; ++i) {
#pragma unroll
            for (int j = 0; j < 64; ++j) h1[j] = fmaf(et[i], W1[(i + 8) * 64 + j], h1[j]);
        }
#pragma unroll
        for (int j = 0; j < 64; ++j) h1[j] = swish(h1[j]);

        // ---- layer 2: h1[64] @ W2[64,64] + b2, swish
        float h2[64];
#pragma unroll
        for (int j = 0; j < 64; ++j) h2[j] = b2[j];
#pragma unroll
        for (int i = 0; i < 64; ++i) {
#pragma unroll
            for (int j = 0; j < 64; ++j) h2[j] = fmaf(h1[i], W2[i * 64 + j], h2[j]);
        }
#pragma unroll
        for (int j = 0; j < 64; ++j) h2[j] = swish(h2[j]);

        // ---- layer 3: h2[64] @ W3[64,32] + b3, swish
        float h3[32];
#pragma unroll
        for (int j = 0; j < 32; ++j) h3[j] = b3[j];
#pragma unroll
        for (int i = 0; i < 64; ++i) {
#pragma unroll
            for (int j = 0; j < 32; ++j) h3[j] = fmaf(h2[i], W3[i * 32 + j], h3[j]);
        }
#pragma unroll
        for (int j = 0; j < 32; ++j) h3[j] = swish(h3[j]);

        // ---- layer 4: h3[32] @ W4[32,8] + b4; Euler update
        float o[8];
#pragma unroll
        for (int j = 0; j < 8; ++j) o[j] = b4[j];
#pragma unroll
        for (int i = 0; i < 32; ++i) {
#pragma unroll
            for (int j = 0; j < 8; ++j) o[j] = fmaf(h3[i], W4[i * 8 + j], o[j]);
        }
#pragma unroll
        for (int j = 0; j < 8; ++j) st[j] = fmaf(dt, o[j], st[j]);
    }

    float4 o0 = make_float4(st[0], st[1], st[2], st[3]);
    float4 o1 = make_float4(st[4], st[5], st[6], st[7]);
    float4* op = reinterpret_cast<float4*>(out + (size_t)row * 8);
    op[0] = o0;
    op[1] = o1;
}

extern "C" void kernel_launch(void* const* d_in, const int* in_sizes, int n_in,
                              void* d_out, int out_size, void* d_ws, size_t ws_size,
                              hipStream_t stream) {
    const float* eta = (const float*)d_in[0];
    const float* W1  = (const float*)d_in[1];
    const float* b1  = (const float*)d_in[2];
    const float* W2  = (const float*)d_in[3];
    const float* b2  = (const float*)d_in[4];
    const float* W3  = (const float*)d_in[5];
    const float* b3  = (const float*)d_in[6];
    const float* W4  = (const float*)d_in[7];
    const float* b4  = (const float*)d_in[8];
    float* out = (float*)d_out;

    const int batch = in_sizes[0] / 8;
    const int block = 256;
    const int grid = (batch + block - 1) / block;
    hipLaunchKernelGGL(noprop_f32_kernel, dim3(grid), dim3(block), 0, stream,
                       eta, W1, b1, W2, b2, W3, b3, W4, b4, out, batch);
}

// Round 3
// 1021.987 us; speedup vs baseline: 14.1595x; 14.1595x over previous
//
#include <hip/hip_runtime.h>
#include <hip/hip_bf16.h>

// NoPropCTMomentNet: 10-step Euler of a 17->64->64->32->8 swish MLP, B=2M rows.
// Round 3: bf16 MFMA (16x16x32). One wave = 16 rows. Weights held as W^T
// A-fragments in VGPRs; activations as B-fragments [feat x 16rows]; the
// D->B layout transpose between layers goes through a per-wave LDS region
// (stride 84 words: b64 writes / b128 reads are bank-uniform). No barriers:
// all LDS traffic is intra-wave. State stays fp32 across steps.

typedef __attribute__((ext_vector_type(8))) short short8;   // 8 bf16 = 4 VGPR
typedef __attribute__((ext_vector_type(4))) float f32x4;

constexpr int NSTEP = 10;
constexpr float DT = 0.1f;

__device__ __forceinline__ unsigned int f2bfu(float x) {
    __hip_bfloat16 h = __float2bfloat16(x);
    unsigned short us; __builtin_memcpy(&us, &h, 2);
    return (unsigned int)us;
}
__device__ __forceinline__ unsigned int pack2(float a, float b) {
    return f2bfu(a) | (f2bfu(b) << 16);
}
__device__ __forceinline__ float swish(float x) {
    return x * __builtin_amdgcn_rcpf(1.0f + __expf(-x));
}
__device__ __forceinline__ short8 mk8(unsigned int w0, unsigned int w1,
                                      unsigned int w2, unsigned int w3) {
    union { unsigned int w[4]; short8 s; } u;
    u.w[0] = w0; u.w[1] = w1; u.w[2] = w2; u.w[3] = w3;
    return u.s;
}

// A-fragment of W^T (chunk c of 16 out-features, k-split s of 32 in-features).
// A[m][k]: m = lane&15 (out-feature 16c+m), k = (lane>>4)*8 + j (in-feature 32s+k).
// W is stored [in][out] row-major, so A[m][k] = W[k_in * NOUT + 16c + m].
template <int NOUT, int KLIM, bool M8>
__device__ __forceinline__ short8 wfrag(const float* __restrict__ W,
                                        int c, int s, int n, int hi) {
    unsigned int w[4];
#pragma unroll
    for (int p = 0; p < 4; ++p) {
        const int k0 = 32 * s + 8 * hi + 2 * p;
        const bool mok = !M8 || (n < 8);
        float a = (mok && (k0     < KLIM)) ? W[(size_t)k0 * NOUT + 16 * c + n]       : 0.0f;
        float b = (mok && (k0 + 1 < KLIM)) ? W[(size_t)(k0 + 1) * NOUT + 16 * c + n] : 0.0f;
        w[p] = pack2(a, b);
    }
    return mk8(w[0], w[1], w[2], w[3]);
}

__global__ __launch_bounds__(256) void noprop_mfma_kernel(
    const float* __restrict__ eta,
    const float* __restrict__ W1, const float* __restrict__ b1,
    const float* __restrict__ W2, const float* __restrict__ b2,
    const float* __restrict__ W3, const float* __restrict__ b3,
    const float* __restrict__ W4, const float* __restrict__ b4,
    float* __restrict__ out, int batch)
{
    const int lane = threadIdx.x & 63;
    const int wid  = threadIdx.x >> 6;
    const int n  = lane & 15;   // batch row within tile (D col / B col / A row)
    const int hi = lane >> 4;   // k-block (A/B) or m-block (C/D)

    // per-wave transpose scratch: [16 rows][84 slots] of u32 (bf16 pairs)
    // slots: ST 0..3 | H1 4..35 | H2 36..67 | H3 68..83
    __shared__ unsigned int lds[4 * 16 * 84];
    unsigned int* Lrow = lds + wid * (16 * 84) + n * 84;
    constexpr int ST = 0, H1 = 4, H2 = 36, H3 = 68;

    // ---- persistent weight fragments (per-wave, loaded once)
    short8 W1f[4], W2f[4][2], W3f[2][2], W4f;
#pragma unroll
    for (int c = 0; c < 4; ++c) W1f[c] = wfrag<64, 17, false>(W1, c, 0, n, hi);
#pragma unroll
    for (int c = 0; c < 4; ++c)
#pragma unroll
        for (int s = 0; s < 2; ++s) W2f[c][s] = wfrag<64, 64, false>(W2, c, s, n, hi);
#pragma unroll
    for (int c = 0; c < 2; ++c)
#pragma unroll
        for (int s = 0; s < 2; ++s) W3f[c][s] = wfrag<32, 64, false>(W3, c, s, n, hi);
    W4f = wfrag<8, 32, true>(W4, 0, 0, n, hi);

    // ---- bias fragments (C/D layout: lane holds m = 4*hi + r of chunk c)
    f32x4 zero4 = {0.f, 0.f, 0.f, 0.f};
    f32x4 B1b[4], B2b[4], B3b[2], B4b;
#pragma unroll
    for (int c = 0; c < 4; ++c) B1b[c] = *(const f32x4*)(b1 + 16 * c + 4 * hi);
#pragma unroll
    for (int c = 0; c < 4; ++c) B2b[c] = *(const f32x4*)(b2 + 16 * c + 4 * hi);
#pragma unroll
    for (int c = 0; c < 2; ++c) B3b[c] = *(const f32x4*)(b3 + 16 * c + 4 * hi);
    B4b = (hi < 2) ? *(const f32x4*)(b4 + 4 * hi) : zero4;

    const int nTiles = batch >> 4;
    const int gwave  = (int)((blockIdx.x * blockDim.x + threadIdx.x) >> 6);
    const int nWaves = (int)((gridDim.x * blockDim.x) >> 6);

    for (int tile = gwave; tile < nTiles; tile += nWaves) {
        const int row = (tile << 4) + n;
        const float* erow = eta + (size_t)row * 8;

        f32x4 e0 = *(const f32x4*)(erow);
        f32x4 e1 = *(const f32x4*)(erow + 4);

        // state in D layout: lane(hi<2) holds st[4hi + r] of row n; fp32 always
        f32x4 stD = zero4;
        if (hi == 0) stD = e0;
        if (hi == 1) stD = e1;

        // eta B-frag words (consumed by hi==1 lanes: k=8..15 -> eta[0..7] of row n)
        unsigned int etaP[4];
        etaP[0] = pack2(e0.x, e0.y); etaP[1] = pack2(e0.z, e0.w);
        etaP[2] = pack2(e1.x, e1.y); etaP[3] = pack2(e1.z, e1.w);

#pragma unroll 1
        for (int step = 0; step < NSTEP; ++step) {
            const float t = DT * (float)step;
            const unsigned int tpack = f2bfu(t);

            // st (D layout, fp32) -> LDS bf16 pairs at slot ST+2hi (+p)
            if (hi < 2) {
                *(uint2*)(Lrow + ST + 2 * hi) =
                    make_uint2(pack2(stD.x, stD.y), pack2(stD.z, stD.w));
            }
            uint4 stv = *(const uint4*)(Lrow + ST);   // features 0..7 of row n

            // build layer-1 B fragment: k 0..7 st | 8..15 eta | 16 t | rest 0
            unsigned int b1w0, b1w1, b1w2, b1w3;
            b1w0 = (hi == 0) ? stv.x : (hi == 1) ? etaP[0] : (hi == 2) ? tpack : 0u;
            b1w1 = (hi == 0) ? stv.y : (hi == 1) ? etaP[1] : 0u;
            b1w2 = (hi == 0) ? stv.z : (hi == 1) ? etaP[2] : 0u;
            b1w3 = (hi == 0) ? stv.w : (hi == 1) ? etaP[3] : 0u;
            short8 Bx = mk8(b1w0, b1w1, b1w2, b1w3);

            // ---- layer 1 (17 -> 64): 4 chunks
            f32x4 a1[4];
#pragma unroll
            for (int c = 0; c < 4; ++c)
                a1[c] = __builtin_amdgcn_mfma_f32_16x16x32_bf16(W1f[c], Bx, B1b[c], 0, 0, 0);
#pragma unroll
            for (int c = 0; c < 4; ++c) {
                *(uint2*)(Lrow + H1 + 8 * c + 2 * hi) =
                    make_uint2(pack2(swish(a1[c].x), swish(a1[c].y)),
                               pack2(swish(a1[c].z), swish(a1[c].w)));
            }
            short8 h1f[2];
#pragma unroll
            for (int s = 0; s < 2; ++s) {
                uint4 v = *(const uint4*)(Lrow + H1 + 16 * s + 4 * hi);
                h1f[s] = mk8(v.x, v.y, v.z, v.w);
            }

            // ---- layer 2 (64 -> 64): 4 chunks x 2 k-splits
            f32x4 a2[4];
#pragma unroll
            for (int c = 0; c < 4; ++c) {
                f32x4 t0 = __builtin_amdgcn_mfma_f32_16x16x32_bf16(W2f[c][0], h1f[0], B2b[c], 0, 0, 0);
                a2[c]    = __builtin_amdgcn_mfma_f32_16x16x32_bf16(W2f[c][1], h1f[1], t0, 0, 0, 0);
            }
#pragma unroll
            for (int c = 0; c < 4; ++c) {
                *(uint2*)(Lrow + H2 + 8 * c + 2 * hi) =
                    make_uint2(pack2(swish(a2[c].x), swish(a2[c].y)),
                               pack2(swish(a2[c].z), swish(a2[c].w)));
            }
            short8 h2f[2];
#pragma unroll
            for (int s = 0; s < 2; ++s) {
                uint4 v = *(const uint4*)(Lrow + H2 + 16 * s + 4 * hi);
                h2f[s] = mk8(v.x, v.y, v.z, v.w);
            }

            // ---- layer 3 (64 -> 32): 2 chunks x 2 k-splits
            f32x4 a3[2];
#pragma unroll
            for (int c = 0; c < 2; ++c) {
                f32x4 t0 = __builtin_amdgcn_mfma_f32_16x16x32_bf16(W3f[c][0], h2f[0], B3b[c], 0, 0, 0);
                a3[c]    = __builtin_amdgcn_mfma_f32_16x16x32_bf16(W3f[c][1], h2f[1], t0, 0, 0, 0);
            }
#pragma unroll
            for (int c = 0; c < 2; ++c) {
                *(uint2*)(Lrow + H3 + 8 * c + 2 * hi) =
                    make_uint2(pack2(swish(a3[c].x), swish(a3[c].y)),
                               pack2(swish(a3[c].z), swish(a3[c].w)));
            }
            uint4 v3 = *(const uint4*)(Lrow + H3 + 4 * hi);
            short8 h3f = mk8(v3.x, v3.y, v3.z, v3.w);

            // ---- layer 4 (32 -> 8) + Euler update (fp32)
            f32x4 a4 = __builtin_amdgcn_mfma_f32_16x16x32_bf16(W4f, h3f, B4b, 0, 0, 0);
            stD.x = fmaf(DT, a4.x, stD.x);
            stD.y = fmaf(DT, a4.y, stD.y);
            stD.z = fmaf(DT, a4.z, stD.z);
            stD.w = fmaf(DT, a4.w, stD.w);
        }

        if (hi < 2) *(f32x4*)(out + (size_t)row * 8 + 4 * hi) = stD;
    }
}

extern "C" void kernel_launch(void* const* d_in, const int* in_sizes, int n_in,
                              void* d_out, int out_size, void* d_ws, size_t ws_size,
                              hipStream_t stream) {
    const float* eta = (const float*)d_in[0];
    const float* W1  = (const float*)d_in[1];
    const float* b1  = (const float*)d_in[2];
    const float* W2  = (const float*)d_in[3];
    const float* b2  = (const float*)d_in[4];
    const float* W3  = (const float*)d_in[5];
    const float* b3  = (const float*)d_in[6];
    const float* W4  = (const float*)d_in[7];
    const float* b4  = (const float*)d_in[8];
    float* out = (float*)d_out;

    const int batch = in_sizes[0] / 8;
    const int block = 256;   // 4 waves
    const int grid  = 2048;  // 8192 waves -> 16 tiles/wave (131072 tiles total)
    hipLaunchKernelGGL(noprop_mfma_kernel, dim3(grid), dim3(block), 0, stream,
                       eta, W1, b1, W2, b2, W3, b3, W4, b4, out, batch);
}

// Round 5
// 993.163 us; speedup vs baseline: 14.5705x; 1.0290x over previous
//
#include <hip/hip_runtime.h>
#include <hip/hip_fp16.h>

// NoPropCTMomentNet: 10-step Euler of a 17->64->64->32->8 swish MLP, B=2M rows.
// Round 5 (= R4 + compile fix): fp16 MFMA + packed-half2 division-free swish.
//  - scaled domain: z = log2(e)*(Wx+b) folded into W1,b1..b3; W4 *= ln2.
//    carried activation h^ = log2e*swish(x) = 0.5z + |z|*q(2^-|z|),
//    q(e) ~= 1/(1+e)-0.5, degree-5 poly => 1 trans/activation (no rcp).
//  - all swish arithmetic packed __half2; cvt_pkrtz is also the LDS pack.
//  - per-wave LDS (stride 52 words): [st|eta|t,0|0] B1 block (one unmasked
//    b128 read) + one reused 32-word H buffer. No barriers (intra-wave only).

typedef __attribute__((ext_vector_type(8))) _Float16 half8;
typedef __attribute__((ext_vector_type(4))) float f32x4;

constexpr int NSTEP = 10;
constexpr float DT = 0.1f;
constexpr float LOG2E = 1.44269504f;
constexpr float LN2   = 0.69314718f;

__device__ __forceinline__ unsigned packh(float a, float b) {
    __half2 h = __floats2half2_rn(a, b);
    unsigned r; __builtin_memcpy(&r, &h, 4); return r;
}
__device__ __forceinline__ unsigned pkrtz(float a, float b) {
    auto z = __builtin_amdgcn_cvt_pkrtz(a, b);   // __fp16 ext_vector(2)
    unsigned r; __builtin_memcpy(&r, &z, 4); return r;
}
__device__ __forceinline__ half8 mk8h(unsigned w0, unsigned w1,
                                      unsigned w2, unsigned w3) {
    union { unsigned w[4]; half8 h; } u;
    u.w[0] = w0; u.w[1] = w1; u.w[2] = w2; u.w[3] = w3;
    return u.h;
}

// packed swish in scaled domain: input 2 f32 preacts (z = log2e * true preact),
// output u32 = 2 f16 of h^ = z*sigma2(z)  (= log2e * swish(true preact))
__device__ __forceinline__ unsigned swish2(float za, float zb) {
    auto zc = __builtin_amdgcn_cvt_pkrtz(za, zb);
    __half2 z; __builtin_memcpy(&z, &zc, 4);
    __half2 az = __habs2(z);
    __half2 e  = h2exp2(__hneg2(az));           // 2^-|z| in (0,1]
    const __half2 C0 = __float2half2_rn( 0.5f);
    const __half2 C1 = __float2half2_rn(-0.996622f);
    const __half2 C2 = __float2half2_rn( 0.956088f);
    const __half2 C3 = __float2half2_rn(-0.777792f);
    const __half2 C4 = __float2half2_rn( 0.426000f);
    const __half2 C5 = __float2half2_rn(-0.107654f);
    __half2 q = __hfma2(e, __hfma2(e, __hfma2(e, __hfma2(e, __hfma2(e, C5, C4), C3), C2), C1), C0);
    __half2 hh = __hfma2(az, q, __hmul2(z, C0));  // 0.5*z + |z|*q
    unsigned r; __builtin_memcpy(&r, &hh, 4);
    return r;
}

// A-fragment of W^T (chunk c of 16 out-features, k-split s), fp16, scaled.
// A[m][k]: m = lane&15 (out-feature 16c+m), k = 8*hi + j (in-feature 32s+k).
template <int NOUT, int KLIM, bool M8>
__device__ __forceinline__ half8 wfragh(const float* __restrict__ W, float scale,
                                        int c, int s, int n, int hi) {
    unsigned w[4];
#pragma unroll
    for (int p = 0; p < 4; ++p) {
        const int k0 = 32 * s + 8 * hi + 2 * p;
        const bool mok = !M8 || (n < 8);
        float a = (mok && (k0     < KLIM)) ? W[(size_t)k0 * NOUT + 16 * c + n] * scale : 0.0f;
        float b = (mok && (k0 + 1 < KLIM)) ? W[(size_t)(k0 + 1) * NOUT + 16 * c + n] * scale : 0.0f;
        w[p] = packh(a, b);
    }
    return mk8h(w[0], w[1], w[2], w[3]);
}

__device__ __forceinline__ f32x4 ldb4s(const float* p, float s) {
    f32x4 v = *(const f32x4*)p;
    v.x *= s; v.y *= s; v.z *= s; v.w *= s;
    return v;
}

__global__ __launch_bounds__(256) void noprop_mfma_kernel(
    const float* __restrict__ eta,
    const float* __restrict__ W1, const float* __restrict__ b1,
    const float* __restrict__ W2, const float* __restrict__ b2,
    const float* __restrict__ W3, const float* __restrict__ b3,
    const float* __restrict__ W4, const float* __restrict__ b4,
    float* __restrict__ out, int batch)
{
    const int lane = threadIdx.x & 63;
    const int wid  = threadIdx.x >> 6;
    const int n  = lane & 15;   // batch row within tile
    const int hi = lane >> 4;   // k-block (A/B) or m-block (C/D)

    // per-wave scratch, stride 52 words/row
    // row layout: [0..3 st | 4..7 eta | 8 t,0 9..15 zeros | 16..47 H buffer]
    __shared__ unsigned int lds[4 * 16 * 52];
    unsigned int* Lrow = lds + wid * (16 * 52) + n * 52;
    constexpr int HB = 16;

    // ---- persistent weight fragments (scaled domain)
    half8 W1f[4], W2f[4][2], W3f[2][2], W4f;
#pragma unroll
    for (int c = 0; c < 4; ++c) W1f[c] = wfragh<64, 17, false>(W1, LOG2E, c, 0, n, hi);
#pragma unroll
    for (int c = 0; c < 4; ++c)
#pragma unroll
        for (int s = 0; s < 2; ++s) W2f[c][s] = wfragh<64, 64, false>(W2, 1.0f, c, s, n, hi);
#pragma unroll
    for (int c = 0; c < 2; ++c)
#pragma unroll
        for (int s = 0; s < 2; ++s) W3f[c][s] = wfragh<32, 64, false>(W3, 1.0f, c, s, n, hi);
    W4f = wfragh<8, 32, true>(W4, LN2, 0, 0, n, hi);

    // ---- bias fragments (C layout), b1..b3 scaled by log2e
    f32x4 zero4 = {0.f, 0.f, 0.f, 0.f};
    f32x4 B1b[4], B2b[4], B3b[2], B4b;
#pragma unroll
    for (int c = 0; c < 4; ++c) B1b[c] = ldb4s(b1 + 16 * c + 4 * hi, LOG2E);
#pragma unroll
    for (int c = 0; c < 4; ++c) B2b[c] = ldb4s(b2 + 16 * c + 4 * hi, LOG2E);
#pragma unroll
    for (int c = 0; c < 2; ++c) B3b[c] = ldb4s(b3 + 16 * c + 4 * hi, LOG2E);
    B4b = (hi < 2) ? *(const f32x4*)(b4 + 4 * hi) : zero4;

    const int nTiles = batch >> 4;
    const int gwave  = (int)((blockIdx.x * blockDim.x + threadIdx.x) >> 6);
    const int nWaves = (int)((gridDim.x * blockDim.x) >> 6);

    for (int tile = gwave; tile < nTiles; tile += nWaves) {
        const int row = (tile << 4) + n;
        const float* erow = eta + (size_t)row * 8;

        f32x4 e0 = *(const f32x4*)(erow);
        f32x4 e1 = *(const f32x4*)(erow + 4);

        // state D-frag: lane(hi<2) holds st[4hi+r] of row n, fp32 always
        f32x4 stD = zero4;
        if (hi == 0) stD = e0;
        if (hi == 1) stD = e1;

        // per-tile LDS init: eta pairs (hi==1 group), zero words 8..15 (hi>=2)
        if (hi == 1)
            *(uint4*)(Lrow + 4) = make_uint4(pkrtz(e0.x, e0.y), pkrtz(e0.z, e0.w),
                                             pkrtz(e1.x, e1.y), pkrtz(e1.z, e1.w));
        if (hi >= 2)
            *(uint4*)(Lrow + 4 * hi) = make_uint4(0u, 0u, 0u, 0u);

#pragma unroll 1
        for (int step = 0; step < NSTEP; ++step) {
            const float t = DT * (float)step;
            __half th = __float2half(t);
            unsigned short tb; __builtin_memcpy(&tb, &th, 2);
            const unsigned tw = (unsigned)tb;

            if (hi < 2)
                *(uint2*)(Lrow + 2 * hi) = make_uint2(pkrtz(stD.x, stD.y), pkrtz(stD.z, stD.w));
            if (hi == 2) Lrow[8] = tw;

            // layer-1 B fragment: one unmasked b128 read of [st|eta|t0|00]
            uint4 bw = *(const uint4*)(Lrow + 4 * hi);
            half8 Bx = mk8h(bw.x, bw.y, bw.z, bw.w);

            // ---- layer 1 (17 -> 64)
            f32x4 a1[4];
#pragma unroll
            for (int c = 0; c < 4; ++c)
                a1[c] = __builtin_amdgcn_mfma_f32_16x16x32_f16(W1f[c], Bx, B1b[c], 0, 0, 0);
#pragma unroll
            for (int c = 0; c < 4; ++c)
                *(uint2*)(Lrow + HB + 8 * c + 2 * hi) =
                    make_uint2(swish2(a1[c].x, a1[c].y), swish2(a1[c].z, a1[c].w));
            half8 h1f[2];
#pragma unroll
            for (int s = 0; s < 2; ++s) {
                uint4 v = *(const uint4*)(Lrow + HB + 16 * s + 4 * hi);
                h1f[s] = mk8h(v.x, v.y, v.z, v.w);
            }

            // ---- layer 2 (64 -> 64), reuses H buffer
            f32x4 a2[4];
#pragma unroll
            for (int c = 0; c < 4; ++c) {
                f32x4 t0 = __builtin_amdgcn_mfma_f32_16x16x32_f16(W2f[c][0], h1f[0], B2b[c], 0, 0, 0);
                a2[c]    = __builtin_amdgcn_mfma_f32_16x16x32_f16(W2f[c][1], h1f[1], t0, 0, 0, 0);
            }
#pragma unroll
            for (int c = 0; c < 4; ++c)
                *(uint2*)(Lrow + HB + 8 * c + 2 * hi) =
                    make_uint2(swish2(a2[c].x, a2[c].y), swish2(a2[c].z, a2[c].w));
            half8 h2f[2];
#pragma unroll
            for (int s = 0; s < 2; ++s) {
                uint4 v = *(const uint4*)(Lrow + HB + 16 * s + 4 * hi);
                h2f[s] = mk8h(v.x, v.y, v.z, v.w);
            }

            // ---- layer 3 (64 -> 32), reuses H buffer again
            f32x4 a3[2];
#pragma unroll
            for (int c = 0; c < 2; ++c) {
                f32x4 t0 = __builtin_amdgcn_mfma_f32_16x16x32_f16(W3f[c][0], h2f[0], B3b[c], 0, 0, 0);
                a3[c]    = __builtin_amdgcn_mfma_f32_16x16x32_f16(W3f[c][1], h2f[1], t0, 0, 0, 0);
            }
#pragma unroll
            for (int c = 0; c < 2; ++c)
                *(uint2*)(Lrow + HB + 8 * c + 2 * hi) =
                    make_uint2(swish2(a3[c].x, a3[c].y), swish2(a3[c].z, a3[c].w));
            uint4 v3 = *(const uint4*)(Lrow + HB + 4 * hi);   // feats 0..31, K=32
            half8 h3f = mk8h(v3.x, v3.y, v3.z, v3.w);

            // ---- layer 4 (32 -> 8, true domain) + Euler update (fp32)
            f32x4 a4 = __builtin_amdgcn_mfma_f32_16x16x32_f16(W4f, h3f, B4b, 0, 0, 0);
            stD.x = fmaf(DT, a4.x, stD.x);
            stD.y = fmaf(DT, a4.y, stD.y);
            stD.z = fmaf(DT, a4.z, stD.z);
            stD.w = fmaf(DT, a4.w, stD.w);
        }

        if (hi < 2) *(f32x4*)(out + (size_t)row * 8 + 4 * hi) = stD;
    }
}

extern "C" void kernel_launch(void* const* d_in, const int* in_sizes, int n_in,
                              void* d_out, int out_size, void* d_ws, size_t ws_size,
                              hipStream_t stream) {
    const float* eta = (const float*)d_in[0];
    const float* W1  = (const float*)d_in[1];
    const float* b1  = (const float*)d_in[2];
    const float* W2  = (const float*)d_in[3];
    const float* b2  = (const float*)d_in[4];
    const float* W3  = (const float*)d_in[5];
    const float* b3  = (const float*)d_in[6];
    const float* W4  = (const float*)d_in[7];
    const float* b4  = (const float*)d_in[8];
    float* out = (float*)d_out;

    const int batch = in_sizes[0] / 8;
    const int block = 256;   // 4 waves
    const int grid  = 2048;  // 8192 waves -> 16 tiles/wave
    hipLaunchKernelGGL(noprop_mfma_kernel, dim3(grid), dim3(block), 0, stream,
                       eta, W1, b1, W2, b2, W3, b3, W4, b4, out, batch);
}